// Round 4
// baseline (311.406 us; speedup 1.0000x reference)
//
#include <hip/hip_runtime.h>
#include <stdint.h>

typedef float    f32x4  __attribute__((ext_vector_type(4)));
typedef short    bf16x8 __attribute__((ext_vector_type(8)));
typedef uint32_t u32;

#define NHW 401408.0   // 32*112*112

__device__ __forceinline__ ushort f2bf(float f) {
  uint32_t u = __float_as_uint(f);
  uint32_t r = u + 0x7FFFu + ((u >> 16) & 1u);   // RNE
  return (ushort)(r >> 16);
}

__device__ __forceinline__ void gload_lds16(const void* g, void* l) {
  typedef __attribute__((address_space(1))) const u32 gu32;
  typedef __attribute__((address_space(3))) u32 lu32;
  __builtin_amdgcn_global_load_lds((gu32*)g, (lu32*)l, 16, 0, 0);
}

// ---- K0: W[o][c][3][3] fp32 -> bf16 in MFMA A-fragment order:
// Wfrag[((tap*2+half)*4+of)*512 + (kg*16+pw)*8 + j] = W[of*16+pw][half*32+kg*8+j]
__global__ __launch_bounds__(256) void prep_weights(const float* __restrict__ Wg,
                                                    ushort* __restrict__ Wfrag) {
  int i = blockIdx.x * 256 + threadIdx.x;    // 36864
  int tap = i >> 12;
  int o   = (i >> 6) & 63;
  int c   = i & 63;
  float w = Wg[(o * 64 + c) * 9 + tap];
  int of = o >> 4, pw = o & 15;
  int half = c >> 5, kg = (c >> 3) & 3, j = c & 7;
  Wfrag[(((tap * 2 + half) * 4 + of) << 9) + ((kg * 16 + pw) << 3) + j] = f2bf(w);
}

// ---- K1: per-channel sum / sumsq
__global__ __launch_bounds__(256) void stats_kernel(const float* __restrict__ x,
                                                    double* __restrict__ sums) {
  int blk = blockIdx.x;                       // n*64 + c
  const float4* p = (const float4*)(x + (size_t)blk * 12544);
  float s = 0.f, q = 0.f;
  for (int i = threadIdx.x; i < 3136; i += 256) {
    float4 v = p[i];
    s += (v.x + v.y) + (v.z + v.w);
    q += v.x * v.x + v.y * v.y + v.z * v.z + v.w * v.w;
  }
#pragma unroll
  for (int off = 32; off > 0; off >>= 1) {
    s += __shfl_down(s, off);
    q += __shfl_down(q, off);
  }
  __shared__ float ls[8];
  int wv = threadIdx.x >> 6;
  if ((threadIdx.x & 63) == 0) { ls[wv] = s; ls[4 + wv] = q; }
  __syncthreads();
  if (threadIdx.x == 0) {
    double S = (double)ls[0] + ls[1] + ls[2] + ls[3];
    double Q = (double)ls[4] + ls[5] + ls[6] + ls[7];
    int c = blk & 63;
    atomicAdd(&sums[c], S);
    atomicAdd(&sums[64 + c], Q);
  }
}

// ---- K2: mean/istd -> per-channel affine: xbn = fma(x, a, d)
__global__ void finalize_kernel(const double* __restrict__ sums,
                                const float* __restrict__ gamma,
                                const float* __restrict__ beta,
                                float* __restrict__ ad) {
  int c = threadIdx.x;                        // 64 threads
  double mean = sums[c] / NHW;
  double var  = sums[64 + c] / NHW - mean * mean;
  double istd = 1.0 / sqrt(var + 1e-4);
  double a = (double)gamma[c] * istd;
  double d = (double)beta[c] - mean * a;
  ad[c]      = (float)a;
  ad[64 + c] = (float)d;
}

// ---- K3: binarize + NCHW->NHWC transpose, w-padded (wp=w+1, 114 slots),
// global layout signs[n][h][wp][c ^ ((wp&7)<<3)] bf16; wp=0,113 zeroed.
// lane = c (64 lanes span c) -> LDS writes 2-way conflict-free.
__global__ __launch_bounds__(256) void binarize_kernel(const float* __restrict__ x,
                                                       const float* __restrict__ ad,
                                                       ushort* __restrict__ signs) {
  __shared__ ushort ls[112 * 64];
  const int n = blockIdx.y, h = blockIdx.x;
  const int t = threadIdx.x;
  const int c = t & 63, q = t >> 6;           // 64 chans x 4 w-quarters
  const float a_c = ad[c], d_c = ad[64 + c];
  const f32x4* src = (const f32x4*)(x + (size_t)(n * 64 + c) * 12544 + h * 112 + q * 28);
#pragma unroll
  for (int i = 0; i < 7; ++i) {
    f32x4 v = src[i];
#pragma unroll
    for (int k = 0; k < 4; ++k) {
      float tt = fmaf(v[k], a_c, d_c);
      ushort s = (tt > 0.f) ? (ushort)0x3F80 : ((tt < 0.f) ? (ushort)0xBF80 : (ushort)0);
      int w = q * 28 + i * 4 + k;
      ls[w * 64 + (c ^ (((w + 1) & 7) << 3))] = s;
    }
  }
  __syncthreads();
  uint4* grow = (uint4*)(signs + (size_t)(n * 112 + h) * 114 * 64);
  const uint4* lsv = (const uint4*)ls;
  uint4 z = {0, 0, 0, 0};
  if (t < 8) grow[t] = z;                  // wp=0 border
  else if (t < 16) grow[904 + t - 8] = z;  // wp=113 border
  for (int i = t; i < 896; i += 256) grow[8 + i] = lsv[i];
}

// ---- K4: conv = implicit GEMM over pre-binarized signs
// block = 8h x 16w x 64o tile, 4 waves (2 h-rows each); LDS = 10 rows x 2304B
// = 23040 B -> 6 blocks/CU, 24 waves/CU.
#define ROWB 2304
__global__ __launch_bounds__(256, 6) void conv_kernel(
    const ushort* __restrict__ signs, const ushort* __restrict__ Wfrag,
    const float* __restrict__ bias, float* __restrict__ out) {
  __shared__ __align__(16) char smem[10 * ROWB];
  const int tid = threadIdx.x, lane = tid & 63, wv = tid >> 6;
  const int w_id = (blockIdx.x & 7) * 392 + (blockIdx.x >> 3);   // 3136 = 8*392
  const int n = w_id / 98, t = w_id - n * 98;
  const int th = t / 7, tw = t - th * 7;
  const int h0 = th * 8, w0 = tw * 16;

  // stage: linear copy of pre-swizzled signs rows, zero out-of-range rows
  for (int r = wv; r < 10; r += 4) {
    int gh = h0 - 1 + r;
    char* ldst = smem + r * ROWB;
    if ((unsigned)gh < 112u) {
      const char* g = (const char*)(signs + ((size_t)(n * 112 + gh) * 114 + w0) * 64);
      gload_lds16(g + lane * 16, ldst);
      gload_lds16(g + 1024 + lane * 16, ldst + 1024);
      if (lane < 16) {
        uint4 v = *(const uint4*)(g + 2048 + lane * 16);
        *(uint4*)(ldst + 2048 + lane * 16) = v;
      }
    } else {
      uint4 z = {0, 0, 0, 0};
      *(uint4*)(ldst + lane * 16) = z;
      *(uint4*)(ldst + 1024 + lane * 16) = z;
      if (lane < 16) *(uint4*)(ldst + 2048 + lane * 16) = z;
    }
  }
  __syncthreads();

  // main loop: A = weights (M=o), B = signs (N=w position). K = 9 taps x 64 c.
  f32x4 acc[4][2] = {};   // [of][pf]
  const int pw = lane & 15, kg = lane >> 4;
  const char* As = smem;
#pragma unroll
  for (int tap = 0; tap < 9; ++tap) {
    const int kh = tap / 3, kw = tap - 3 * kh;
    const int sw = pw + kw;
    const int swz = (sw & 7) << 4;
#pragma unroll
    for (int half = 0; half < 2; ++half) {
      const int cb = half * 64 + kg * 16;
      bf16x8 bf[2], af[4];
#pragma unroll
      for (int pf = 0; pf < 2; ++pf) {
        int sh = 2 * wv + pf + kh;
        bf[pf] = *(const bf16x8*)(As + (sh * 18 + sw) * 128 + (cb ^ swz));
      }
#pragma unroll
      for (int of = 0; of < 4; ++of)
        af[of] = *(const bf16x8*)(Wfrag + (((tap * 2 + half) * 4 + of) << 9) + (lane << 3));
#pragma unroll
      for (int of = 0; of < 4; ++of)
#pragma unroll
        for (int pf = 0; pf < 2; ++pf)
          acc[of][pf] = __builtin_amdgcn_mfma_f32_16x16x32_bf16(af[of], bf[pf],
                                                                acc[of][pf], 0, 0, 0);
    }
  }

  // epilogue: D row = o-in-frag = kg*4+r, col = w = pw. Direct register stores.
  float bv[4][4];
#pragma unroll
  for (int of = 0; of < 4; ++of)
#pragma unroll
    for (int r = 0; r < 4; ++r) bv[of][r] = bias[of * 16 + kg * 4 + r];
#pragma unroll
  for (int of = 0; of < 4; ++of)
#pragma unroll
    for (int pf = 0; pf < 2; ++pf) {
      size_t ob = ((size_t)(n * 64 + of * 16 + kg * 4) * 112 + (h0 + 2 * wv + pf)) * 112
                  + w0 + pw;
#pragma unroll
      for (int r = 0; r < 4; ++r)
        out[ob + (size_t)r * 12544] = fmaxf(acc[of][pf][r] + bv[of][r], 0.f);
    }
}

// ---- fallback conv (reads x directly, stages+transposes in LDS)
__global__ __launch_bounds__(256, 3) void conv_fallback(
    const float* __restrict__ x, const float* __restrict__ ad,
    const ushort* __restrict__ Wfrag, const float* __restrict__ bias,
    float* __restrict__ out) {
  __shared__ __align__(16) char smem[41472];
  const int tid = threadIdx.x, lane = tid & 63, wv = tid >> 6;
  int w_id = (blockIdx.x & 7) * 196 + (blockIdx.x >> 3);
  const int n = w_id / 49, t = w_id - n * 49;
  const int th = t / 7, tw = t - th * 7;
  const int h0 = th * 16, w0 = tw * 16;
  {
    const int c = tid & 63, rg = tid >> 6;
    const float a_c = ad[c], d_c = ad[64 + c];
    const float* xc = x + ((size_t)(n * 64 + c)) * 12544;
    ushort* Au = (ushort*)smem;
    for (int r = rg; r < 18; r += 4) {
      int gh = h0 - 1 + r;
      bool hok = (unsigned)gh < 112u;
      const float* xrow = xc + gh * 112;
      ushort* rowp = Au + r * (18 * 64);
#pragma unroll
      for (int sw = 0; sw < 18; ++sw) {
        int gw = w0 - 1 + sw;
        ushort v = 0;
        if (hok && (unsigned)gw < 112u) {
          float tt = fmaf(xrow[gw], a_c, d_c);
          v = (tt > 0.f) ? (ushort)0x3F80 : ((tt < 0.f) ? (ushort)0xBF80 : (ushort)0);
        }
        rowp[sw * 64 + (c ^ ((sw & 7) << 3))] = v;
      }
    }
  }
  __syncthreads();
  f32x4 acc[4][4] = {};
  const int pw = lane & 15, kg = lane >> 4;
  const char* As = smem;
#pragma unroll
  for (int tap = 0; tap < 9; ++tap) {
    const int kh = tap / 3, kw = tap - 3 * kh;
    const int sw = pw + kw;
    const int swz = (sw & 7) << 4;
#pragma unroll
    for (int half = 0; half < 2; ++half) {
      const int cb = half * 64 + kg * 16;
      bf16x8 bf[4], af[4];
#pragma unroll
      for (int pf = 0; pf < 4; ++pf) {
        int sh = 4 * wv + pf + kh;
        bf[pf] = *(const bf16x8*)(As + (sh * 18 + sw) * 128 + (cb ^ swz));
      }
#pragma unroll
      for (int of = 0; of < 4; ++of)
        af[of] = *(const bf16x8*)(Wfrag + (((tap * 2 + half) * 4 + of) << 9) + (lane << 3));
#pragma unroll
      for (int of = 0; of < 4; ++of)
#pragma unroll
        for (int pf = 0; pf < 4; ++pf)
          acc[of][pf] = __builtin_amdgcn_mfma_f32_16x16x32_bf16(af[of], bf[pf],
                                                                acc[of][pf], 0, 0, 0);
    }
  }
  float bv[4][4];
#pragma unroll
  for (int of = 0; of < 4; ++of)
#pragma unroll
    for (int r = 0; r < 4; ++r) bv[of][r] = bias[of * 16 + kg * 4 + r];
#pragma unroll
  for (int of = 0; of < 4; ++of)
#pragma unroll
    for (int pf = 0; pf < 4; ++pf) {
      size_t ob = ((size_t)(n * 64 + of * 16 + kg * 4) * 112 + (h0 + 4 * wv + pf)) * 112
                  + w0 + pw;
#pragma unroll
      for (int r = 0; r < 4; ++r)
        out[ob + (size_t)r * 12544] = fmaxf(acc[of][pf][r] + bv[of][r], 0.f);
    }
}

extern "C" void kernel_launch(void* const* d_in, const int* in_sizes, int n_in,
                              void* d_out, int out_size, void* d_ws, size_t ws_size,
                              hipStream_t stream) {
  (void)in_sizes; (void)n_in; (void)out_size;
  const float* x     = (const float*)d_in[0];
  const float* gamma = (const float*)d_in[1];
  const float* beta  = (const float*)d_in[2];
  const float* Wg    = (const float*)d_in[3];
  const float* bias  = (const float*)d_in[4];
  float* out = (float*)d_out;

  char* ws = (char*)d_ws;
  float*  ad    = (float*)ws;              // 128 f32
  double* sums  = (double*)(ws + 512);     // 128 f64
  ushort* Wfrag = (ushort*)(ws + 1536);    // 73728 B
  ushort* signs = (ushort*)(ws + 76288);   // 32*112*114*64*2 = 52,297,728 B
  const size_t need = 76288 + (size_t)32 * 112 * 114 * 128;

  hipMemsetAsync(sums, 0, 128 * sizeof(double), stream);
  prep_weights<<<dim3(144), dim3(256), 0, stream>>>(Wg, Wfrag);
  stats_kernel<<<dim3(2048), dim3(256), 0, stream>>>(x, sums);
  finalize_kernel<<<dim3(1), dim3(64), 0, stream>>>(sums, gamma, beta, ad);
  if (ws_size >= need) {
    binarize_kernel<<<dim3(112, 32), dim3(256), 0, stream>>>(x, ad, signs);
    conv_kernel<<<dim3(3136), dim3(256), 0, stream>>>(signs, Wfrag, bias, out);
  } else {
    conv_fallback<<<dim3(1568), dim3(256), 0, stream>>>(x, ad, Wfrag, bias, out);
  }
}

// Round 7
// 248.175 us; speedup vs baseline: 1.2548x; 1.2548x over previous
//
#include <hip/hip_runtime.h>
#include <stdint.h>

typedef float    f32x4 __attribute__((ext_vector_type(4)));
typedef int      i32x4 __attribute__((ext_vector_type(4)));
typedef uint32_t u32;

#define NHW 401408.0   // 32*112*112

__device__ __forceinline__ void gload_lds16(const void* g, void* l) {
  typedef __attribute__((address_space(1))) const u32 gu32;
  typedef __attribute__((address_space(3))) u32 lu32;
  __builtin_amdgcn_global_load_lds((gu32*)g, (lu32*)l, 16, 0, 0);
}

// ---- K0: per-o i8 quantization of W, in MFMA A-fragment order.
// Wq[(tap*4+of)*1024 + (kg*16 + (o&15))*16 + j] = rint(W[o][c=kg*16+j][tap]/s_o)
// lane l of fragment (tap,of): o = of*16 + (l&15), c = (l>>4)*16 + j.
__global__ __launch_bounds__(64) void prep_weights(const float* __restrict__ Wg,
                                                   int8_t* __restrict__ Wq,
                                                   float* __restrict__ sc) {
  int o = blockIdx.x, c = threadIdx.x;    // 64 blocks x 64 threads
  float w[9]; float m = 0.f;
#pragma unroll
  for (int tap = 0; tap < 9; ++tap) {
    w[tap] = Wg[(o * 64 + c) * 9 + tap];
    m = fmaxf(m, fabsf(w[tap]));
  }
#pragma unroll
  for (int off = 32; off > 0; off >>= 1) m = fmaxf(m, __shfl_xor(m, off));
  float s = m / 127.f;
  float inv = (s > 0.f) ? 1.f / s : 0.f;
  if (c == 0) sc[o] = s;
  int of = o >> 4, m16 = o & 15, kg = c >> 4, j = c & 15;
#pragma unroll
  for (int tap = 0; tap < 9; ++tap) {
    int q = (int)rintf(w[tap] * inv);
    q = q > 127 ? 127 : (q < -127 ? -127 : q);
    Wq[(tap * 4 + of) * 1024 + (kg * 16 + m16) * 16 + j] = (int8_t)q;
  }
}

// ---- K1: per-channel sum / sumsq
__global__ __launch_bounds__(256) void stats_kernel(const float* __restrict__ x,
                                                    double* __restrict__ sums) {
  int blk = blockIdx.x;                       // n*64 + c
  const float4* p = (const float4*)(x + (size_t)blk * 12544);
  float s = 0.f, q = 0.f;
  for (int i = threadIdx.x; i < 3136; i += 256) {
    float4 v = p[i];
    s += (v.x + v.y) + (v.z + v.w);
    q += v.x * v.x + v.y * v.y + v.z * v.z + v.w * v.w;
  }
#pragma unroll
  for (int off = 32; off > 0; off >>= 1) {
    s += __shfl_down(s, off);
    q += __shfl_down(q, off);
  }
  __shared__ float ls[8];
  int wv = threadIdx.x >> 6;
  if ((threadIdx.x & 63) == 0) { ls[wv] = s; ls[4 + wv] = q; }
  __syncthreads();
  if (threadIdx.x == 0) {
    double S = (double)ls[0] + ls[1] + ls[2] + ls[3];
    double Q = (double)ls[4] + ls[5] + ls[6] + ls[7];
    int c = blk & 63;
    atomicAdd(&sums[c], S);
    atomicAdd(&sums[64 + c], Q);
  }
}

// ---- K2: mean/istd -> per-channel affine: xbn = fma(x, a, d)
__global__ void finalize_kernel(const double* __restrict__ sums,
                                const float* __restrict__ gamma,
                                const float* __restrict__ beta,
                                float* __restrict__ ad) {
  int c = threadIdx.x;                        // 64 threads
  double mean = sums[c] / NHW;
  double var  = sums[64 + c] / NHW - mean * mean;
  double istd = 1.0 / sqrt(var + 1e-4);
  double a = (double)gamma[c] * istd;
  double d = (double)beta[c] - mean * a;
  ad[c]      = (float)a;
  ad[64 + c] = (float)d;
}

// ---- K3: binarize + NCHW->NHWC(i8) transpose, w-padded (wp=w+1, 114 slots)
// signs[n][h][wp][c] int8; wp=0 and wp=113 zeroed.  LDS u32 transpose.
__global__ __launch_bounds__(256) void binarize_kernel(const float* __restrict__ x,
                                                       const float* __restrict__ ad,
                                                       u32* __restrict__ signs) {
  __shared__ u32 buf[64 * 29];                // [c][wu 0..27] +1 pad
  const int n = blockIdx.y, h = blockIdx.x, t = threadIdx.x;
  {
    const int c = t & 63, q = t >> 6;         // lanes span c -> coalesced loads
    const float a_c = ad[c], d_c = ad[64 + c];
    const f32x4* src = (const f32x4*)(x + (size_t)(n * 64 + c) * 12544 + h * 112 + q * 28);
#pragma unroll
    for (int i = 0; i < 7; ++i) {
      f32x4 v = src[i];
      u32 p = 0;
#pragma unroll
      for (int k = 0; k < 4; ++k) {
        float tt = fmaf(v[k], a_c, d_c);
        u32 b = (tt > 0.f) ? 0x01u : ((tt < 0.f) ? 0xFFu : 0x00u);
        p |= b << (8 * k);
      }
      buf[c * 29 + q * 7 + i] = p;            // 29 coprime 32 -> conflict-free
    }
  }
  __syncthreads();
  u32* row = signs + (size_t)(n * 112 + h) * 114 * 16;
  const int cq = t & 15, wg = t >> 4;
  if (t < 16) row[t] = 0;                     // wp=0 border
  else if (t < 32) row[113 * 16 + (t - 16)] = 0;  // wp=113 border
#pragma unroll
  for (int pass = 0; pass < 7; ++pass) {
    int w = wg + 16 * pass;                   // 0..111
    int sh = (w & 3) * 8;
    u32 o = 0;
#pragma unroll
    for (int j = 0; j < 4; ++j) {
      u32 v = buf[(cq * 4 + j) * 29 + (w >> 2)];
      o |= ((v >> sh) & 0xFFu) << (8 * j);
    }
    row[(w + 1) * 16 + cq] = o;               // lanes: 16 full 64B segments
  }
}

// ---- K4: conv = i8 implicit GEMM, full-width tile 4h x 112w x 64o.
// 4 waves (1 h-row each, 7 w-frags), LDS = 6 signs rows x 7296 B = 43776.
// K-step = tap (K=64 = all channels). Epilogue: LDS transpose -> 256B stores.
#define SROW 7296   // 114 * 64 bytes
__global__ __launch_bounds__(256, 2) void conv_kernel(
    const int8_t* __restrict__ signs, const int8_t* __restrict__ Wq,
    const float* __restrict__ sc, const float* __restrict__ bias,
    float* __restrict__ out) {
  __shared__ __align__(16) char smem[6 * SROW];
  const int tid = threadIdx.x, lane = tid & 63, wv = tid >> 6;
  const int b = (blockIdx.x & 7) * 112 + (blockIdx.x >> 3);   // 896 = 8*112
  const int n = b / 28, th = b - n * 28;
  const int h0 = th * 4;

  // stage 6 full-width sign rows (linear gload_lds; no swizzle needed)
  for (int r = wv; r < 6; r += 4) {
    int gh = h0 - 1 + r;
    char* dst = smem + r * SROW;
    if ((unsigned)gh < 112u) {
      const char* g = (const char*)signs + (size_t)(n * 112 + gh) * SROW;
#pragma unroll
      for (int off = 0; off < 7168; off += 1024)
        gload_lds16(g + off + lane * 16, dst + off);
      if (lane < 8) gload_lds16(g + 7168 + lane * 16, dst + 7168);
    } else {
      uint4 z = {0, 0, 0, 0};
      for (int off = lane * 16; off < SROW; off += 1024) *(uint4*)(dst + off) = z;
    }
  }
  __syncthreads();

  // main loop: A = weights (M=o), B = signs (N=w). 9 tap-steps of K=64.
  i32x4 acc[4][7] = {};
  const int pw = lane & 15, kg = lane >> 4;
#pragma unroll
  for (int tap = 0; tap < 9; ++tap) {
    const int kh = tap / 3, kw = tap - 3 * kh;
    i32x4 af[4], bf[7];
#pragma unroll
    for (int of = 0; of < 4; ++of)
      af[of] = *(const i32x4*)(Wq + (tap * 4 + of) * 1024 + lane * 16);
#pragma unroll
    for (int wf = 0; wf < 7; ++wf)
      bf[wf] = *(const i32x4*)(smem + ((wv + kh) * 114 + wf * 16 + pw + kw) * 64 + kg * 16);
#pragma unroll
    for (int of = 0; of < 4; ++of)
#pragma unroll
      for (int wf = 0; wf < 7; ++wf)
        acc[of][wf] = __builtin_amdgcn_mfma_i32_16x16x64_i8(af[of], bf[wf],
                                                            acc[of][wf], 0, 0, 0);
  }
  __syncthreads();                        // done reading signs LDS

  // epilogue: per-wave patch [16 o][114 w] f32 (7296 B), then 256B row stores
  float* patch = (float*)smem + wv * (16 * 114);
  const size_t obase = ((size_t)n * 64) * 12544 + (size_t)(h0 + wv) * 112;
#pragma unroll
  for (int of = 0; of < 4; ++of) {
    float sv[4], bv[4];
#pragma unroll
    for (int r = 0; r < 4; ++r) {
      int o = of * 16 + kg * 4 + r;
      sv[r] = sc[o]; bv[r] = bias[o];
    }
#pragma unroll
    for (int wf = 0; wf < 7; ++wf)
#pragma unroll
      for (int r = 0; r < 4; ++r)
        patch[(kg * 4 + r) * 114 + wf * 16 + pw] =
            fmaxf(fmaf((float)acc[of][wf][r], sv[r], bv[r]), 0.f);
    __builtin_amdgcn_s_barrier();   // wave-internal ordering is enough, but cheap
#pragma unroll
    for (int o = 0; o < 16; ++o) {
      float v0 = patch[o * 114 + lane];
      out[obase + (size_t)(of * 16 + o) * 12544 + lane] = v0;
      if (lane < 48) {
        float v1 = patch[o * 114 + 64 + lane];
        out[obase + (size_t)(of * 16 + o) * 12544 + 64 + lane] = v1;
      }
    }
    __builtin_amdgcn_s_barrier();
  }
}

extern "C" void kernel_launch(void* const* d_in, const int* in_sizes, int n_in,
                              void* d_out, int out_size, void* d_ws, size_t ws_size,
                              hipStream_t stream) {
  (void)in_sizes; (void)n_in; (void)out_size; (void)ws_size;
  const float* x     = (const float*)d_in[0];
  const float* gamma = (const float*)d_in[1];
  const float* beta  = (const float*)d_in[2];
  const float* Wg    = (const float*)d_in[3];
  const float* bias  = (const float*)d_in[4];
  float* out = (float*)d_out;

  char* ws = (char*)d_ws;
  float*   ad    = (float*)ws;              // 128 f32
  double*  sums  = (double*)(ws + 512);     // 128 f64
  float*   sc    = (float*)(ws + 1536);     // 64 f32 (i8 scales)
  int8_t*  Wq    = (int8_t*)(ws + 1792);    // 36864 B fragment-ordered i8 weights
  u32*     signs = (u32*)(ws + 38656);      // 32*112*114*64 i8 = 26,148,864 B

  hipMemsetAsync(sums, 0, 128 * sizeof(double), stream);
  prep_weights<<<dim3(64), dim3(64), 0, stream>>>(Wg, Wq, sc);
  stats_kernel<<<dim3(2048), dim3(256), 0, stream>>>(x, sums);
  finalize_kernel<<<dim3(1), dim3(64), 0, stream>>>(sums, gamma, beta, ad);
  binarize_kernel<<<dim3(112, 32), dim3(256), 0, stream>>>(x, ad, signs);
  conv_kernel<<<dim3(896), dim3(256), 0, stream>>>((const int8_t*)signs, Wq, sc, bias, out);
}

// Round 9
// 236.536 us; speedup vs baseline: 1.3165x; 1.0492x over previous
//
#include <hip/hip_runtime.h>
#include <stdint.h>

typedef float    f32x4 __attribute__((ext_vector_type(4)));
typedef int      i32x4 __attribute__((ext_vector_type(4)));
typedef uint32_t u32;

#define NHW 401408.0   // 32*112*112

__device__ __forceinline__ void gload_lds16(const void* g, void* l) {
  typedef __attribute__((address_space(1))) const u32 gu32;
  typedef __attribute__((address_space(3))) u32 lu32;
  __builtin_amdgcn_global_load_lds((gu32*)g, (lu32*)l, 16, 0, 0);
}

// ---- K0: per-o i8 quantization of W, in MFMA A-fragment order.
// Wq[(tap*4+of)*1024 + (kg*16 + (o&15))*16 + j] = rint(W[o][c=kg*16+j][tap]/s_o)
__global__ __launch_bounds__(64) void prep_weights(const float* __restrict__ Wg,
                                                   int8_t* __restrict__ Wq,
                                                   float* __restrict__ sc) {
  int o = blockIdx.x, c = threadIdx.x;    // 64 blocks x 64 threads
  float w[9]; float m = 0.f;
#pragma unroll
  for (int tap = 0; tap < 9; ++tap) {
    w[tap] = Wg[(o * 64 + c) * 9 + tap];
    m = fmaxf(m, fabsf(w[tap]));
  }
#pragma unroll
  for (int off = 32; off > 0; off >>= 1) m = fmaxf(m, __shfl_xor(m, off));
  float s = m / 127.f;
  float inv = (s > 0.f) ? 1.f / s : 0.f;
  if (c == 0) sc[o] = s;
  int of = o >> 4, m16 = o & 15, kg = c >> 4, j = c & 15;
#pragma unroll
  for (int tap = 0; tap < 9; ++tap) {
    int q = (int)rintf(w[tap] * inv);
    q = q > 127 ? 127 : (q < -127 ? -127 : q);
    Wq[(tap * 4 + of) * 1024 + (kg * 16 + m16) * 16 + j] = (int8_t)q;
  }
}

// ---- K1: per-channel sum / sumsq
__global__ __launch_bounds__(256) void stats_kernel(const float* __restrict__ x,
                                                    double* __restrict__ sums) {
  int blk = blockIdx.x;                       // n*64 + c
  const float4* p = (const float4*)(x + (size_t)blk * 12544);
  float s = 0.f, q = 0.f;
  for (int i = threadIdx.x; i < 3136; i += 256) {
    float4 v = p[i];
    s += (v.x + v.y) + (v.z + v.w);
    q += v.x * v.x + v.y * v.y + v.z * v.z + v.w * v.w;
  }
#pragma unroll
  for (int off = 32; off > 0; off >>= 1) {
    s += __shfl_down(s, off);
    q += __shfl_down(q, off);
  }
  __shared__ float ls[8];
  int wv = threadIdx.x >> 6;
  if ((threadIdx.x & 63) == 0) { ls[wv] = s; ls[4 + wv] = q; }
  __syncthreads();
  if (threadIdx.x == 0) {
    double S = (double)ls[0] + ls[1] + ls[2] + ls[3];
    double Q = (double)ls[4] + ls[5] + ls[6] + ls[7];
    int c = blk & 63;
    atomicAdd(&sums[c], S);
    atomicAdd(&sums[64 + c], Q);
  }
}

// ---- K2: mean/istd -> per-channel affine: xbn = fma(x, a, d)
__global__ void finalize_kernel(const double* __restrict__ sums,
                                const float* __restrict__ gamma,
                                const float* __restrict__ beta,
                                float* __restrict__ ad) {
  int c = threadIdx.x;                        // 64 threads
  double mean = sums[c] / NHW;
  double var  = sums[64 + c] / NHW - mean * mean;
  double istd = 1.0 / sqrt(var + 1e-4);
  double a = (double)gamma[c] * istd;
  double d = (double)beta[c] - mean * a;
  ad[c]      = (float)a;
  ad[64 + c] = (float)d;
}

// ---- K3: binarize + NCHW->NHWC(i8) transpose, w-padded (wp=w+1, 114 slots)
// signs[n][h][wp][c] int8; wp=0 and wp=113 zeroed.  LDS u32 transpose.
__global__ __launch_bounds__(256) void binarize_kernel(const float* __restrict__ x,
                                                       const float* __restrict__ ad,
                                                       u32* __restrict__ signs) {
  __shared__ u32 buf[64 * 29];                // [c][wu 0..27] +1 pad
  const int n = blockIdx.y, h = blockIdx.x, t = threadIdx.x;
  {
    const int c = t & 63, q = t >> 6;         // lanes span c -> coalesced loads
    const float a_c = ad[c], d_c = ad[64 + c];
    const f32x4* src = (const f32x4*)(x + (size_t)(n * 64 + c) * 12544 + h * 112 + q * 28);
#pragma unroll
    for (int i = 0; i < 7; ++i) {
      f32x4 v = src[i];
      u32 p = 0;
#pragma unroll
      for (int k = 0; k < 4; ++k) {
        float tt = fmaf(v[k], a_c, d_c);
        u32 b = (tt > 0.f) ? 0x01u : ((tt < 0.f) ? 0xFFu : 0x00u);
        p |= b << (8 * k);
      }
      buf[c * 29 + q * 7 + i] = p;            // 29 coprime 32 -> conflict-free
    }
  }
  __syncthreads();
  u32* row = signs + (size_t)(n * 112 + h) * 114 * 16;
  const int cq = t & 15, wg = t >> 4;
  if (t < 16) row[t] = 0;                     // wp=0 border
  else if (t < 32) row[113 * 16 + (t - 16)] = 0;  // wp=113 border
#pragma unroll
  for (int pass = 0; pass < 7; ++pass) {
    int w = wg + 16 * pass;                   // 0..111
    int sh = (w & 3) * 8;
    u32 o = 0;
#pragma unroll
    for (int j = 0; j < 4; ++j) {
      u32 v = buf[(cq * 4 + j) * 29 + (w >> 2)];
      o |= ((v >> sh) & 0xFFu) << (8 * j);
    }
    row[(w + 1) * 16 + cq] = o;               // 256B contiguous per pass
  }
}

// ---- K4: conv = i8 implicit GEMM, full-width tile 4h x 112w x 64o.
// 512 thr = 8 waves: wave = (h-row r4 = wv&3, of-pair p = wv>>2), acc[2][7].
// LDS = 6 signs rows x 7296 B = 43776 -> 2 blocks/CU, 16 waves/CU.
// Direct register stores (full-width => same wave writes both 64B line halves).
#define SROW 7296   // 114 * 64 bytes
__global__ __launch_bounds__(512, 4) void conv_kernel(
    const int8_t* __restrict__ signs, const int8_t* __restrict__ Wq,
    const float* __restrict__ sc, const float* __restrict__ bias,
    float* __restrict__ out) {
  __shared__ __align__(16) char smem[6 * SROW];
  const int tid = threadIdx.x, lane = tid & 63, wv = tid >> 6;
  const int r4 = wv & 3;                      // h-row in tile
  const int p  = wv >> 2;                     // of-pair: of in {2p, 2p+1}
  const int b = (blockIdx.x & 7) * 112 + (blockIdx.x >> 3);   // 896 = 8*112
  const int n = b / 28, th = b - n * 28;
  const int h0 = th * 4;

  // stage 6 full-width sign rows (waves 0..5, one row each; linear gload_lds)
  if (wv < 6) {
    int gh = h0 - 1 + wv;
    char* dst = smem + wv * SROW;
    if ((unsigned)gh < 112u) {
      const char* g = (const char*)signs + (size_t)(n * 112 + gh) * SROW;
#pragma unroll
      for (int off = 0; off < 7168; off += 1024)
        gload_lds16(g + off + lane * 16, dst + off);
      if (lane < 8) gload_lds16(g + 7168 + lane * 16, dst + 7168);
    } else {
      uint4 z = {0, 0, 0, 0};
      for (int off = lane * 16; off < SROW; off += 1024) *(uint4*)(dst + off) = z;
    }
  }
  __syncthreads();

  // main loop: A = weights (M=o), B = signs (N=w). 9 tap-steps of K=64.
  i32x4 acc[2][7] = {};
  const int pw = lane & 15, kg = lane >> 4;
#pragma unroll
  for (int tap = 0; tap < 9; ++tap) {
    const int kh = tap / 3, kw = tap - 3 * kh;
    i32x4 af0 = *(const i32x4*)(Wq + (tap * 4 + 2 * p) * 1024 + lane * 16);
    i32x4 af1 = *(const i32x4*)(Wq + (tap * 4 + 2 * p + 1) * 1024 + lane * 16);
    i32x4 bf[7];
#pragma unroll
    for (int wf = 0; wf < 7; ++wf)
      bf[wf] = *(const i32x4*)(smem + ((r4 + kh) * 114 + wf * 16 + pw + kw) * 64 + kg * 16);
#pragma unroll
    for (int wf = 0; wf < 7; ++wf) {
      acc[0][wf] = __builtin_amdgcn_mfma_i32_16x16x64_i8(af0, bf[wf], acc[0][wf], 0, 0, 0);
      acc[1][wf] = __builtin_amdgcn_mfma_i32_16x16x64_i8(af1, bf[wf], acc[1][wf], 0, 0, 0);
    }
  }

  // epilogue: direct register stores. D row = o-in-frag = kg*4+rr, col = w = pw.
  const int h = h0 + r4;
#pragma unroll
  for (int i = 0; i < 2; ++i) {
    float sv[4], bv[4];
#pragma unroll
    for (int rr = 0; rr < 4; ++rr) {
      int o = (2 * p + i) * 16 + kg * 4 + rr;
      sv[rr] = sc[o]; bv[rr] = bias[o];
    }
#pragma unroll
    for (int rr = 0; rr < 4; ++rr) {
      int o = (2 * p + i) * 16 + kg * 4 + rr;
      float* orow = out + ((size_t)(n * 64 + o) * 112 + h) * 112;
#pragma unroll
      for (int wf = 0; wf < 7; ++wf)
        orow[wf * 16 + pw] = fmaxf(fmaf((float)acc[i][wf][rr], sv[rr], bv[rr]), 0.f);
    }
  }
}

extern "C" void kernel_launch(void* const* d_in, const int* in_sizes, int n_in,
                              void* d_out, int out_size, void* d_ws, size_t ws_size,
                              hipStream_t stream) {
  (void)in_sizes; (void)n_in; (void)out_size; (void)ws_size;
  const float* x     = (const float*)d_in[0];
  const float* gamma = (const float*)d_in[1];
  const float* beta  = (const float*)d_in[2];
  const float* Wg    = (const float*)d_in[3];
  const float* bias  = (const float*)d_in[4];
  float* out = (float*)d_out;

  char* ws = (char*)d_ws;
  float*   ad    = (float*)ws;              // 128 f32
  double*  sums  = (double*)(ws + 512);     // 128 f64
  float*   sc    = (float*)(ws + 1536);     // 64 f32 (i8 scales)
  int8_t*  Wq    = (int8_t*)(ws + 1792);    // 36864 B fragment-ordered i8 weights
  u32*     signs = (u32*)(ws + 38656);      // 32*112*114*64 i8 = 26,148,864 B

  hipMemsetAsync(sums, 0, 128 * sizeof(double), stream);
  prep_weights<<<dim3(64), dim3(64), 0, stream>>>(Wg, Wq, sc);
  stats_kernel<<<dim3(2048), dim3(256), 0, stream>>>(x, sums);
  finalize_kernel<<<dim3(1), dim3(64), 0, stream>>>(sums, gamma, beta, ad);
  binarize_kernel<<<dim3(112, 32), dim3(256), 0, stream>>>(x, ad, signs);
  conv_kernel<<<dim3(896), dim3(512), 0, stream>>>((const int8_t*)signs, Wq, sc, bias, out);
}